// Round 1
// baseline (473.440 us; speedup 1.0000x reference)
//
#include <hip/hip_runtime.h>

#define KK 48
#define PADS 45
#define STOPS 47
#define NEGF (-10000.0f)

__device__ __forceinline__ float2 pk_fma(float2 a, float2 b, float2 c) {
    float2 d;
    asm("v_pk_fma_f32 %0, %1, %2, %3" : "=v"(d) : "v"(a), "v"(b), "v"(c));
    return d;
}

// One wave (64 lanes) per batch element; lane i owns state i (lanes 48..63 dead).
// Exp-space forward recurrence with two-level (PAD vs rest) offset tracking.
__global__ void __launch_bounds__(64)
crf_fwd(const float* __restrict__ h, const float* __restrict__ msk,
        const float* __restrict__ trans, float* __restrict__ out)
{
    const int lane = threadIdx.x;
    const int b = blockIdx.x;
    const int li = (lane < KK) ? lane : (KK - 1);   // clamp for safe loads
    const bool alive = (lane < KK) && (lane != PADS);

    // E row of this lane's state in registers (PAD row and dead lanes zeroed).
    // NEG entries underflow to 0 in expf — exactly the terms the reference's
    // fp32 LSE also drops.
    float2 er[24];
#pragma unroll
    for (int k = 0; k < 24; ++k) {
        const float e0 = __expf(trans[li * KK + 2 * k]);
        const float e1 = __expf(trans[li * KK + 2 * k + 1]);
        er[k].x = alive ? e0 : 0.0f;
        er[k].y = alive ? e1 : 0.0f;
    }
    // Final-row weights exp(trans[STOP, i]) (cols PAD/STOP underflow to 0).
    const float efin = (lane < KK) ? __expf(trans[STOPS * KK + lane]) : 0.0f;

    __shared__ float4 ush4[2][16];   // u double buffer (64 floats each)

    // Level-1 init: score0 = NEG everywhere except STOP(=level-0).
    // u = exp(score - Cg) with Cg = NEG  ->  1 on all states except PAD, STOP.
    float uown = (lane < KK && lane != PADS && lane != STOPS) ? 1.0f : 0.0f;
    ((float*)ush4[0])[lane] = uown;

    float Cg = NEGF;   // running offset of the level-1 vector
    float d  = 0.0f;   // d = p + NEG - Cg ; p0 = 0 (level-0 mass on STOP)

    const float* hb = h + (size_t)b * (1024 * KK);
    const float* mb = msk + (size_t)b * 1024;

    // Emit prefetch pipeline: current group + 3 groups ahead (12 steps ~ HBM latency).
    float ec[4], e1r[4], e2r[4], e3r[4];
#pragma unroll
    for (int s = 0; s < 4; ++s) {
        ec[s]  = hb[(0 * 4 + s) * KK + li];
        e1r[s] = hb[(1 * 4 + s) * KK + li];
        e2r[s] = hb[(2 * 4 + s) * KK + li];
        e3r[s] = hb[(3 * 4 + s) * KK + li];
    }
    float4 mk  = *(const float4*)(mb);
    float4 mp0 = *(const float4*)(mb + 4);
    float4 mp1 = *(const float4*)(mb + 8);
    float4 mp2 = *(const float4*)(mb + 12);

    for (int g = 0; g < 256; ++g) {
        // Renorm bookkeeping (applied by folding rm into step 0's output).
        float m = uown;
#pragma unroll
        for (int off = 32; off >= 1; off >>= 1)
            m = fmaxf(m, __shfl_xor(m, off));
        const float rm = 1.0f / m;
        const float lm = __logf(m);
        const float mku[4] = {mk.x, mk.y, mk.z, mk.w};

#pragma unroll
        for (int s = 0; s < 4; ++s) {
            const float* uprev = (const float*)ush4[s & 1];
            float* unext = (float*)ush4[(s & 1) ^ 1];

            const float P = __expf(d);          // level-0 -> level-1 coupling
            const float me = ec[s];             // emit[t][lane]
            const float m45 = __shfl(me, PADS); // emit[t][PAD] broadcast

            float2 a0 = make_float2(0.f, 0.f), a1 = a0, a2 = a0, a3 = a0;
#pragma unroll
            for (int k = 0; k < 12; k += 2) {
                const float4 ua = ((const float4*)uprev)[k];
                const float4 ub = ((const float4*)uprev)[k + 1];
                a0 = pk_fma(er[2 * k + 0], make_float2(ua.x, ua.y), a0);
                a1 = pk_fma(er[2 * k + 1], make_float2(ua.z, ua.w), a1);
                a2 = pk_fma(er[2 * k + 2], make_float2(ub.x, ub.y), a2);
                a3 = pk_fma(er[2 * k + 3], make_float2(ub.z, ub.w), a3);
            }
            const float w = ((a0.x + a0.y) + (a1.x + a1.y))
                          + ((a2.x + a2.y) + (a3.x + a3.y)) + P;

            float un = __expf(me) * w;
            const float scale = (s == 0) ? rm : 1.0f;   // fold renorm into step 0
            un *= scale;
            un = alive ? un : 0.0f;
            un = (mku[s] != 0.0f) ? un : (uown * scale); // mask: keep (re-scaled repr)
            unext[lane] = un;
            uown = un;

            if (s == 0) d -= lm;                         // Cg grows by lm
            d += (mku[s] != 0.0f) ? m45 : 0.0f;          // p += emit[t][PAD]
        }
        Cg += lm;

        // Rotate emit/mask pipelines; issue loads for group g+4 (clamped tail).
        const int gn = (g + 4 < 256) ? (g + 4) : 255;
#pragma unroll
        for (int s = 0; s < 4; ++s) {
            ec[s] = e1r[s]; e1r[s] = e2r[s]; e2r[s] = e3r[s];
            e3r[s] = hb[(gn * 4 + s) * KK + li];
        }
        mk = mp0; mp0 = mp1; mp1 = mp2;
        mp2 = *(const float4*)(mb + gn * 4);
    }

    // out[b] = Cg + LSE(d, log(sum_i u[i] * exp(trans[STOP, i])))
    float v = uown * efin;
#pragma unroll
    for (int off = 32; off >= 1; off >>= 1)
        v += __shfl_xor(v, off);
    if (lane == 0) {
        const float b1 = __logf(v);
        const float mx = fmaxf(d, b1);
        const float mn = fminf(d, b1);
        out[b] = Cg + mx + __logf(1.0f + __expf(mn - mx));
    }
}

extern "C" void kernel_launch(void* const* d_in, const int* in_sizes, int n_in,
                              void* d_out, int out_size, void* d_ws, size_t ws_size,
                              hipStream_t stream) {
    const float* h     = (const float*)d_in[0];   // (512, 1024, 48) fp32
    const float* mask  = (const float*)d_in[1];   // (512, 1024) fp32
    const float* trans = (const float*)d_in[2];   // (48, 48) fp32
    float* out = (float*)d_out;                   // (512,) fp32
    crf_fwd<<<512, 64, 0, stream>>>(h, mask, trans, out);
}

// Round 2
// 410.180 us; speedup vs baseline: 1.1542x; 1.1542x over previous
//
#include <hip/hip_runtime.h>

#define KK 48
#define PADS 45
#define STOPS 47
#define NEGF (-10000.0f)

__device__ __forceinline__ float2 pk_fma(float2 a, float2 b, float2 c) {
    float2 d;
    asm("v_pk_fma_f32 %0, %1, %2, %3" : "=v"(d) : "v"(a), "v"(b), "v"(c));
    return d;
}
__device__ __forceinline__ float readlane_f(float v, int lane) {
    return __int_as_float(__builtin_amdgcn_readlane(__float_as_int(v), lane));
}
__device__ __forceinline__ float readlane0_f(float v) {
    return __int_as_float(__builtin_amdgcn_readfirstlane(__float_as_int(v)));
}

// One wave per batch element; lane i owns state i (lanes 48..63 dead).
// Exp-space forward recurrence, two-level (PAD vs rest) offset tracking.
// R2: no ds_swizzle/ds_bpermute anywhere in the step — renorm via
// readfirstlane(u[0]) (states stay within ~e^25 of each other), PAD emit via
// readlane at prefetch time, exp(emit) precomputed off the critical path.
__global__ void __launch_bounds__(64)
crf_fwd(const float* __restrict__ h, const float* __restrict__ msk,
        const float* __restrict__ trans, float* __restrict__ out)
{
    const int lane = threadIdx.x;
    const int b = blockIdx.x;
    const int li = (lane < KK) ? lane : (KK - 1);   // clamp for safe loads
    const bool alive = (lane < KK) && (lane != PADS);

    // E row of this lane's state in registers (PAD row / dead lanes zeroed).
    float2 er[24];
#pragma unroll
    for (int k = 0; k < 24; ++k) {
        const float e0 = __expf(trans[li * KK + 2 * k]);
        const float e1 = __expf(trans[li * KK + 2 * k + 1]);
        er[k].x = alive ? e0 : 0.0f;
        er[k].y = alive ? e1 : 0.0f;
    }
    const float efin = (lane < KK) ? __expf(trans[STOPS * KK + lane]) : 0.0f;

    __shared__ float4 ush4[2][16];   // u double buffer (64 floats each)

    // u = exp(score - Cg), Cg = NEG  ->  1 on all states except PAD, STOP.
    float uown = (lane < KK && lane != PADS && lane != STOPS) ? 1.0f : 0.0f;
    ((float*)ush4[0])[lane] = uown;

    float Cg = NEGF;   // running offset of the level-1 vector
    float d  = 0.0f;   // d = p + NEG - Cg ; p0 = 0 (level-0 mass on STOP)

    const float* hb = h + (size_t)b * (1024 * KK);
    const float* mb = msk + (size_t)b * 1024;

    // Pipeline: current group pre-processed (eme = exp(emit), m45 = PAD emit),
    // plus 3 raw groups in flight (12 steps ~ HBM latency).
    float eme[4], m45s[4];
    float r1[4], r2[4], r3[4];
    {
        float r0[4];
#pragma unroll
        for (int s = 0; s < 4; ++s) {
            r0[s] = hb[(0 * 4 + s) * KK + li];
            r1[s] = hb[(1 * 4 + s) * KK + li];
            r2[s] = hb[(2 * 4 + s) * KK + li];
            r3[s] = hb[(3 * 4 + s) * KK + li];
        }
#pragma unroll
        for (int s = 0; s < 4; ++s) {
            m45s[s] = readlane_f(r0[s], PADS);
            eme[s]  = alive ? __expf(r0[s]) : 0.0f;
        }
    }
    float4 mk  = *(const float4*)(mb);
    float4 mp0 = *(const float4*)(mb + 4);
    float4 mp1 = *(const float4*)(mb + 8);
    float4 mp2 = *(const float4*)(mb + 12);

    for (int g = 0; g < 256; ++g) {
        // Renorm off u[0] (wave-uniform via readfirstlane; no LDS pipe).
        const float m0 = readlane0_f(uown);
        const float rm = __builtin_amdgcn_rcpf(m0);
        const float lm = -__logf(rm);        // consistent with applied scale
        const float mku[4] = {mk.x, mk.y, mk.z, mk.w};

#pragma unroll
        for (int s = 0; s < 4; ++s) {
            const float* uprev = (const float*)ush4[s & 1];
            float* unext = (float*)ush4[(s & 1) ^ 1];

            const float P = __expf(d);       // level-0 -> level-1 coupling

            float2 a0 = make_float2(0.f, 0.f), a1 = a0, a2 = a0, a3 = a0;
#pragma unroll
            for (int k = 0; k < 12; k += 2) {
                const float4 ua = ((const float4*)uprev)[k];
                const float4 ub = ((const float4*)uprev)[k + 1];
                a0 = pk_fma(er[2 * k + 0], make_float2(ua.x, ua.y), a0);
                a1 = pk_fma(er[2 * k + 1], make_float2(ua.z, ua.w), a1);
                a2 = pk_fma(er[2 * k + 2], make_float2(ub.x, ub.y), a2);
                a3 = pk_fma(er[2 * k + 3], make_float2(ub.z, ub.w), a3);
            }
            const float2 s01 = make_float2(a0.x + a1.x, a0.y + a1.y);
            const float2 s23 = make_float2(a2.x + a3.x, a2.y + a3.y);
            const float w = (s01.x + s23.x) + (s01.y + s23.y) + P;

            const float scale = (s == 0) ? rm : 1.0f;   // fold renorm in
            float un = eme[s] * w * scale;              // eme==0 kills dead lanes
            un = (mku[s] != 0.0f) ? un : (uown * scale);
            unext[lane] = un;
            uown = un;

            if (s == 0) d -= lm;
            d += (mku[s] != 0.0f) ? m45s[s] : 0.0f;     // p += emit[t][PAD]
        }
        Cg += lm;

        // Rotate pipelines; preprocess next group; load group g+4 (clamped).
        const int gn = (g + 4 < 256) ? (g + 4) : 255;
#pragma unroll
        for (int s = 0; s < 4; ++s) {
            m45s[s] = readlane_f(r1[s], PADS);
            eme[s]  = alive ? __expf(r1[s]) : 0.0f;
            r1[s] = r2[s]; r2[s] = r3[s];
            r3[s] = hb[(gn * 4 + s) * KK + li];
        }
        mk = mp0; mp0 = mp1; mp1 = mp2;
        mp2 = *(const float4*)(mb + gn * 4);
    }

    // out[b] = Cg + LSE(d, log(sum_i u[i] * exp(trans[STOP, i])))
    float v = uown * efin;
#pragma unroll
    for (int off = 32; off >= 1; off >>= 1)
        v += __shfl_xor(v, off);
    if (lane == 0) {
        const float b1 = __logf(v);
        const float mx = fmaxf(d, b1);
        const float mn = fminf(d, b1);
        out[b] = Cg + mx + __logf(1.0f + __expf(mn - mx));
    }
}

extern "C" void kernel_launch(void* const* d_in, const int* in_sizes, int n_in,
                              void* d_out, int out_size, void* d_ws, size_t ws_size,
                              hipStream_t stream) {
    const float* h     = (const float*)d_in[0];   // (512, 1024, 48) fp32
    const float* mask  = (const float*)d_in[1];   // (512, 1024) fp32
    const float* trans = (const float*)d_in[2];   // (48, 48) fp32
    float* out = (float*)d_out;                   // (512,) fp32
    crf_fwd<<<512, 64, 0, stream>>>(h, mask, trans, out);
}